// Round 2
// baseline (199.979 us; speedup 1.0000x reference)
//
#include <hip/hip_runtime.h>
#include <hip/hip_bf16.h>

typedef unsigned short u16;
typedef unsigned int   u32;
typedef unsigned long long u64;

#define BATCH 4096
#define IDIM  1024
#define ODIM  1024
#define NDEG  9                 // degree 8 -> 9 basis terms
#define KA    8192              // GEMM K: d=1..8 only (d=0 is rank-1)
#define NZ    4                 // split-K factor (64 tiles x 4 = 256 blocks = 1/CU)
#define KZ    (KA / NZ)         // 2048 per z-slice
#define GBK   64                // K-tile
#define NT    (KZ / GBK)        // 32 K-tiles per block

typedef __attribute__((ext_vector_type(8))) short short8_t;   // 8 bf16 = 4 VGPRs
typedef __attribute__((ext_vector_type(4))) float f32x4;

// round-to-nearest-even f32 -> bf16
__device__ __forceinline__ u16 f2bf(float f) {
    union { float f; u32 u; } v; v.f = f;
    u32 r = v.u + 0x7FFFu + ((v.u >> 16) & 1u);
    return (u16)(r >> 16);
}
__device__ __forceinline__ u32 pack2bf(float lo, float hi) {
    return (u32)f2bf(lo) | ((u32)f2bf(hi) << 16);
}
__device__ __forceinline__ float bf2f(u16 h) {
    union { u32 u; float f; } v; v.u = (u32)h << 16; return v.f;
}

// async 16B global -> LDS (wave-uniform LDS base + lane*16; global src per-lane)
__device__ __forceinline__ void gl_lds16(const u16* g, u16* l) {
    __builtin_amdgcn_global_load_lds(
        (const __attribute__((address_space(1))) void*)g,
        (__attribute__((address_space(3))) void*)l,
        16, 0, 0);
}

#define BARRIER()   __builtin_amdgcn_s_barrier()
// rule #18: sched_barrier(0) right after an inline-asm lgkmcnt so pure-reg MFMAs
// cannot be hoisted above the wait by the scheduler.
#define WAIT_LGKM0() do { asm volatile("s_waitcnt lgkmcnt(0)" ::: "memory"); \
                          __builtin_amdgcn_sched_barrier(0); } while (0)
#define WAIT_LGKM8() asm volatile("s_waitcnt lgkmcnt(8)" ::: "memory")
#define WAIT_VM4()  asm volatile("s_waitcnt vmcnt(4)" ::: "memory")
#define WAIT_VM0()  asm volatile("s_waitcnt vmcnt(0)" ::: "memory")

// ---------------------------------------------------------------------------
// Fused prep (single dispatch, block-role split) — unchanged from R1.
// ---------------------------------------------------------------------------
#define PB_TI 128
#define PB_TO 8
#define PB_J  (PB_TO * NDEG)    // 72
#define PB_LS 132               // LDS row stride (u16): 264 B, u64-aligned rows

#define NB_B   1024
#define NB_A   2048

__global__ void prep_kernel(const float* __restrict__ x,
                            const float* __restrict__ c,
                            u16* __restrict__ A, u16* __restrict__ Bt,
                            float* __restrict__ Pr) {
    __shared__ u16 lds[PB_J * PB_LS];             // 19 KB (B-blocks only)
    const int bb  = blockIdx.x;
    const int tid = threadIdx.x;

    if (bb < NB_B) {
        const int i0 = (bb & 7) * PB_TI;
        const int o0 = (bb >> 3) * PB_TO;
        const float* src = c + (size_t)i0 * (ODIM * NDEG) + (size_t)o0 * NDEG;
#pragma unroll
        for (int t = 0; t < 36; ++t) {            // 9216 floats / 256 threads
            int f  = t * 256 + tid;
            int ii = f / PB_J;
            int j  = f - ii * PB_J;
            float v = src[(size_t)ii * (ODIM * NDEG) + j];
            lds[j * PB_LS + ii] = f2bf(v);
        }
        __syncthreads();

        // ---- rank-1 column sums from the d=0 LDS row ----
        {
            int o   = tid >> 5;                   // 0..7
            int sub = tid & 31;                   // 32 threads per o
            const u16* row = lds + (o * NDEG) * PB_LS + sub * 4;
            float s = bf2f(row[0]) + bf2f(row[1]) + bf2f(row[2]) + bf2f(row[3]);
#pragma unroll
            for (int m = 16; m >= 1; m >>= 1)     // stays within 32-lane halves
                s += __shfl_xor(s, m, 64);
            if (sub == 0)
                Pr[(size_t)(bb & 7) * ODIM + o0 + o] = s;
        }

#pragma unroll
        for (int t = 0; t < 9; ++t) {             // 72*32 u64 groups / 256 thr
            int g   = t * 256 + tid;
            int j   = g >> 5;                     // 0..71
            int ii4 = (g & 31) << 2;
            int o   = j / NDEG;
            int d   = j - o * NDEG;
            if (d != 0) {
                u64 v = *(const u64*)(lds + j * PB_LS + ii4);
                *(u64*)(Bt + (size_t)(o0 + o) * KA + (d - 1) * 1024 + i0 + ii4) = v;
            }
        }
    } else {
        // ---- A basis (planes d=1..8): thread handles 8 consecutive i ----
        int t  = (bb - NB_B) * 256 + tid;         // 0..524287
        int b  = t >> 7;
        int i8 = (t & 127) << 3;
        const float4* xv = (const float4*)(x + ((size_t)t << 3));
        float4 xa = xv[0], xb = xv[1];
        float th[8] = {tanhf(xa.x), tanhf(xa.y), tanhf(xa.z), tanhf(xa.w),
                       tanhf(xb.x), tanhf(xb.y), tanhf(xb.z), tanhf(xb.w)};
        float va[8], vb[8];
#pragma unroll
        for (int j = 0; j < 8; ++j) { va[j] = 2.0f; vb[j] = th[j]; }
        u16* dst = A + (size_t)b * KA + i8;
        uint4 w;
        w.x = pack2bf(th[0], th[1]); w.y = pack2bf(th[2], th[3]);
        w.z = pack2bf(th[4], th[5]); w.w = pack2bf(th[6], th[7]);
        *(uint4*)dst = w;                          // d=1 plane
#pragma unroll
        for (int d = 2; d < NDEG; ++d) {
            float nx[8];
#pragma unroll
            for (int j = 0; j < 8; ++j) {
                nx[j] = th[j] * vb[j] + va[j];
                va[j] = vb[j]; vb[j] = nx[j];
            }
            w.x = pack2bf(nx[0], nx[1]); w.y = pack2bf(nx[2], nx[3]);
            w.z = pack2bf(nx[4], nx[5]); w.w = pack2bf(nx[6], nx[7]);
            *(uint4*)(dst + (size_t)(d - 1) * 1024) = w;
        }
    }
}

// ---------------------------------------------------------------------------
// GEMM: 256x256 tile, BK=64, 8 waves (2M x 4N, 128x64 per wave), split-K z=4.
// Faithful m201-style HOMOGENEOUS 4-phase schedule: every phase =
//   {12 ds_read_b128 (8 A + 4 B for THIS quadrant, re-read from LDS) +
//    2 gl_lds stages + lgkmcnt(8) + barrier + lgkmcnt(0) + 16 MFMA + barrier}
// Quadrant order: Q00 -> Q01 -> Q11 -> Q10.
// Staging (region-safe: stage only after a region's last LDS reader):
//   P1: tile t+1 A insts {1,3}  -> buf[(t+1)&1]   (last read: t-1's P4)
//   P2: tile t+1 B insts {0,1}  -> buf[(t+1)&1]   (last read: t-1's P4)
//   P3: tile t+2 A insts {0,2}  -> buf[t&1]       (last read: t's P2)
//   P4: tile t+2 B insts {2,3}  -> buf[t&1]       (last read: t's P3)
// Counted wait: vmcnt(4) at end of P4 (t+2's 4 loads stay in flight);
// vmcnt(0) only at the tail. Never drained mid-stream (T4).
// T2 XOR chunk-swizzle kept (0 bank conflicts, R1-verified); T5 setprio kept.
// ---------------------------------------------------------------------------
__global__ __launch_bounds__(512, 2)
void gemm_kernel(const u16* __restrict__ A, const u16* __restrict__ B,
                 float* __restrict__ P, float* __restrict__ out) {
    // [buf][slot s = row*8 + physChunk][8 u16]; phys = logical ^ (row&7)
    __shared__ __align__(16) u16 ldsA[2][16384];   // 64 KB
    __shared__ __align__(16) u16 ldsB[2][16384];   // 64 KB

    const int tid  = threadIdx.x;
    const int lane = tid & 63;
    const int wave = tid >> 6;       // 0..7
    const int quad = lane >> 4;
    const int l15  = lane & 15;
    const int wm   = wave >> 2;      // 0..1  (row half)
    const int wn   = wave & 3;       // 0..3  (col group)

    const int bid = blockIdx.x;      // 0..255
    const int z   = bid >> 6;        // 0..3 K-slice
    const int loc = bid & 63;
    const int swz = (loc & 7) * 8 + (loc >> 3);   // XCD-contiguous (64%8==0)
    const int bm  = swz >> 2;        // 0..15
    const int bn  = swz & 3;         // 0..3
    const int kStart = z * KZ;

    // staging sources at tile 0: inst i covers tile rows [i*64, i*64+64)
    const u16* gA[4]; const u16* gB[4];
#pragma unroll
    for (int i = 0; i < 4; ++i) {
        int s  = i * 512 + tid;                   // 16B slot 0..2047
        int r  = s >> 3;                          // tile row 0..255
        int sc = (s & 7) ^ (r & 7);               // pre-swizzled source chunk
        gA[i] = A + (size_t)(bm * 256 + r) * KA + kStart + sc * 8;
        gB[i] = B + (size_t)(bn * 256 + r) * KA + kStart + sc * 8;
    }

    f32x4 acc[8][4];
#pragma unroll
    for (int i = 0; i < 8; ++i)
#pragma unroll
        for (int j = 0; j < 4; ++j)
            acc[i][j] = (f32x4){0.f, 0.f, 0.f, 0.f};

    // stage helpers: tile w, inst i
#define STAGE_A(i, w) gl_lds16(gA[i] + (size_t)(w) * GBK, \
                               &ldsA[(w) & 1][(i) * 4096 + tid * 8])
#define STAGE_B(i, w) gl_lds16(gB[i] + (size_t)(w) * GBK, \
                               &ldsB[(w) & 1][(i) * 4096 + tid * 8])

    // prologue: tile0 fully (8), tile1's A{0,2} B{2,3} (4); wait tile0 only.
#pragma unroll
    for (int i = 0; i < 4; ++i) { STAGE_A(i, 0); STAGE_B(i, 0); }
    STAGE_A(0, 1); STAGE_A(2, 1); STAGE_B(2, 1); STAGE_B(3, 1);
    WAIT_VM4();                                   // tile0's 8 retired
    BARRIER();

    // per-lane ds_read constants (u16 units); row&7 == l15&7 for all frag rows
    const int pc0  = quad ^ (l15 & 7);            // kk=0 phys chunk
    const int pc1  = (4 + quad) ^ (l15 & 7);      // kk=1
    const int rowA0 = wm * 128 + l15;             // + mh*64 + m*16
    const int rowB0 = wn * 32 + l15;              // + nh*128 + n*16

    short8_t af[4][2], bfq[2][2];

#define READ_A(lA, MH)                                                        \
    _Pragma("unroll")                                                         \
    for (int m = 0; m < 4; ++m) {                                             \
        int ro = (rowA0 + (MH) * 64 + m * 16) * 64;                           \
        af[m][0] = *(const short8_t*)((lA) + ro + pc0 * 8);                   \
        af[m][1] = *(const short8_t*)((lA) + ro + pc1 * 8);                   \
    }
#define READ_B(lB, NH)                                                        \
    _Pragma("unroll")                                                         \
    for (int n = 0; n < 2; ++n) {                                             \
        int ro = (rowB0 + (NH) * 128 + n * 16) * 64;                          \
        bfq[n][0] = *(const short8_t*)((lB) + ro + pc0 * 8);                  \
        bfq[n][1] = *(const short8_t*)((lB) + ro + pc1 * 8);                  \
    }
#define MFMA_Q(MH, NH)                                                        \
    __builtin_amdgcn_s_setprio(1);                                            \
    _Pragma("unroll")                                                         \
    for (int kk = 0; kk < 2; ++kk)                                            \
        _Pragma("unroll")                                                     \
        for (int m = 0; m < 4; ++m)                                           \
            _Pragma("unroll")                                                 \
            for (int n = 0; n < 2; ++n)                                       \
                acc[(MH) * 4 + m][(NH) * 2 + n] =                             \
                    __builtin_amdgcn_mfma_f32_16x16x32_bf16(                  \
                        af[m][kk], bfq[n][kk],                                \
                        acc[(MH) * 4 + m][(NH) * 2 + n], 0, 0, 0);            \
    __builtin_amdgcn_s_setprio(0);

    for (int t = 0; t < NT; ++t) {
        const u16* lA = ldsA[t & 1];
        const u16* lB = ldsB[t & 1];
        const bool s1 = (t + 1 < NT);
        const bool s2 = (t + 2 < NT);

        // ---- P1: Q(0,0) ----
        READ_A(lA, 0); READ_B(lB, 0);
        if (s1) { STAGE_A(1, t + 1); STAGE_A(3, t + 1); }
        WAIT_LGKM8();
        BARRIER();
        WAIT_LGKM0();
        MFMA_Q(0, 0);
        BARRIER();

        // ---- P2: Q(0,1) ----
        READ_A(lA, 0); READ_B(lB, 1);
        if (s1) { STAGE_B(0, t + 1); STAGE_B(1, t + 1); }
        WAIT_LGKM8();
        BARRIER();
        WAIT_LGKM0();
        MFMA_Q(0, 1);
        BARRIER();

        // ---- P3: Q(1,1) ----
        READ_A(lA, 1); READ_B(lB, 1);
        if (s2) { STAGE_A(0, t + 2); STAGE_A(2, t + 2); }
        WAIT_LGKM8();
        BARRIER();
        WAIT_LGKM0();
        MFMA_Q(1, 1);
        BARRIER();

        // ---- P4: Q(1,0) ----
        READ_A(lA, 1); READ_B(lB, 0);
        if (s2) { STAGE_B(2, t + 2); STAGE_B(3, t + 2); }
        WAIT_LGKM8();
        BARRIER();
        WAIT_LGKM0();
        MFMA_Q(1, 0);
        if (s2)       WAIT_VM4();    // t+1 fully landed; t+2's 4 in flight
        else if (s1)  WAIT_VM0();    // tail: drain everything for last tile
        BARRIER();
    }

    // epilogue: C/D layout col = lane&15, row = quad*4 + reg  [m89-verified]
    // z=0 writes straight into out; z>=1 into partial planes (reduce adds).
    float* C = (z == 0) ? out : P + (size_t)(z - 1) * (BATCH * ODIM);
#pragma unroll
    for (int mh = 0; mh < 2; ++mh)
#pragma unroll
        for (int m = 0; m < 4; ++m)
#pragma unroll
            for (int nh = 0; nh < 2; ++nh)
#pragma unroll
                for (int n = 0; n < 2; ++n) {
                    int row0 = bm * 256 + wm * 128 + mh * 64 + m * 16 + quad * 4;
                    int col  = bn * 256 + nh * 128 + wn * 32 + n * 16 + l15;
#pragma unroll
                    for (int r = 0; r < 4; ++r)
                        C[(size_t)(row0 + r) * ODIM + col] = acc[mh * 4 + m][nh * 2 + n][r];
                }
}

// out = out(z0) + P[0..2] + 2 * sum_blk Pr[blk][o]   (split-K + rank-1 term)
__global__ void reduce_kernel(const float* __restrict__ P,
                              const float* __restrict__ Pr,
                              float* __restrict__ out) {
    int t  = blockIdx.x * 256 + threadIdx.x;      // over BATCH*ODIM/4
    int o4 = t & 255;                             // f32x4 column index
    f32x4 a = ((const f32x4*)out)[t];
    a += ((const f32x4*)P)[t];
    a += ((const f32x4*)(P + (size_t)BATCH * ODIM))[t];
    a += ((const f32x4*)(P + 2 * (size_t)BATCH * ODIM))[t];
    f32x4 r = (f32x4){0.f, 0.f, 0.f, 0.f};
#pragma unroll
    for (int blk = 0; blk < 8; ++blk)
        r += ((const f32x4*)Pr)[blk * 256 + o4];  // hot in L2 (32 KB table)
    ((f32x4*)out)[t] = a + r + r;                 // + 2*r  (V0 = 2)
}

extern "C" void kernel_launch(void* const* d_in, const int* in_sizes, int n_in,
                              void* d_out, int out_size, void* d_ws, size_t ws_size,
                              hipStream_t stream) {
    const float* x      = (const float*)d_in[0];   // [4096,1024] f32
    const float* coeffs = (const float*)d_in[1];   // [1024,1024,9] f32
    float* out = (float*)d_out;                    // [4096,1024] f32
    (void)ws_size;

    u16*   A  = (u16*)d_ws;                        // 67.1 MB
    u16*   Bt = A + (size_t)BATCH * KA;            // 16.8 MB
    float* Pr = (float*)(Bt + (size_t)ODIM * KA);  // 32 KB rank-1 partials
    float* P  = Pr + 8 * ODIM;                     // 50.3 MB (3 split-K planes)
    // total ws: 134.3 MB

    prep_kernel<<<NB_B + NB_A, 256, 0, stream>>>(x, coeffs, A, Bt, Pr);
    gemm_kernel<<<256, 512, 0, stream>>>(A, Bt, P, out);
    reduce_kernel<<<BATCH * ODIM / 1024, 256, 0, stream>>>(P, Pr, out);
}

// Round 3
// 176.972 us; speedup vs baseline: 1.1300x; 1.1300x over previous
//
#include <hip/hip_runtime.h>
#include <hip/hip_bf16.h>

typedef unsigned short u16;
typedef unsigned int   u32;
typedef unsigned long long u64;

#define BATCH 4096
#define IDIM  1024
#define ODIM  1024
#define NDEG  9                 // degree 8 -> 9 basis terms
#define KA    8192              // GEMM K: d=1..8 only (d=0 is rank-1)
#define KAH   (KA / 2)          // 4096 per split-K half

typedef __attribute__((ext_vector_type(8))) short short8_t;   // 8 bf16 = 4 VGPRs
typedef __attribute__((ext_vector_type(4))) float f32x4;

// round-to-nearest-even f32 -> bf16
__device__ __forceinline__ u16 f2bf(float f) {
    union { float f; u32 u; } v; v.f = f;
    u32 r = v.u + 0x7FFFu + ((v.u >> 16) & 1u);
    return (u16)(r >> 16);
}
__device__ __forceinline__ u32 pack2bf(float lo, float hi) {
    return (u32)f2bf(lo) | ((u32)f2bf(hi) << 16);
}
__device__ __forceinline__ float bf2f(u16 h) {
    union { u32 u; float f; } v; v.u = (u32)h << 16; return v.f;
}

// fast tanh: tanh(v) = (e^2v - 1)/(e^2v + 1) via v_exp_f32 (2^x) + v_rcp
// + 1 Newton step. rel err ~1e-6 << bf16 ulp (4e-3) -> same bf16 bits as
// tanhf for (essentially) all inputs; clamp keeps u finite (N(0,1) inputs
// never reach it anyway).
__device__ __forceinline__ float fast_tanh(float v) {
    float c = fminf(fmaxf(v, -9.0f), 9.0f);
    float u = __builtin_amdgcn_exp2f(c * 2.8853900817779268f);  // e^(2c)
    float d = u + 1.0f;
    float r = __builtin_amdgcn_rcpf(d);
    r = r * (2.0f - d * r);                       // Newton: ~2^-26
    return (u - 1.0f) * r;
}

// async 16B global -> LDS (wave-uniform LDS base + lane*16)
__device__ __forceinline__ void gl_lds16(const u16* g, u16* l) {
    __builtin_amdgcn_global_load_lds(
        (const __attribute__((address_space(1))) void*)g,
        (__attribute__((address_space(3))) void*)l,
        16, 0, 0);
}

// ---------------------------------------------------------------------------
// Fused prep (single dispatch, block-role split):
//   blocks [0, 1024)    : Bt[o][k=(d-1)*1024+i] <- coeffs[i][o][d], d=1..8
//                         + rank-1 partials sum_i c[i,o,0]
//   blocks [1024, 3072) : A[b][k=(d-1)*1024+i] <- V_d(tanh(x[b,i])), d=1..8
//                         (8 i per thread, 16B stores)
// ---------------------------------------------------------------------------
#define PB_TI 128
#define PB_TO 8
#define PB_J  (PB_TO * NDEG)    // 72
#define PB_LS 132               // LDS row stride (u16): 264 B, u64-aligned rows

#define NB_B   1024
#define NB_A   2048

__global__ void prep_kernel(const float* __restrict__ x,
                            const float* __restrict__ c,
                            u16* __restrict__ A, u16* __restrict__ Bt,
                            float* __restrict__ Pr) {
    __shared__ u16 lds[PB_J * PB_LS];             // 19 KB (B-blocks only)
    const int bb  = blockIdx.x;
    const int tid = threadIdx.x;

    if (bb < NB_B) {
        const int i0 = (bb & 7) * PB_TI;
        const int o0 = (bb >> 3) * PB_TO;
        const float* src = c + (size_t)i0 * (ODIM * NDEG) + (size_t)o0 * NDEG;
#pragma unroll
        for (int t = 0; t < 36; ++t) {            // 9216 floats / 256 threads
            int f  = t * 256 + tid;
            int ii = f / PB_J;
            int j  = f - ii * PB_J;
            float v = src[(size_t)ii * (ODIM * NDEG) + j];
            lds[j * PB_LS + ii] = f2bf(v);
        }
        __syncthreads();

        // ---- rank-1 column sums from the d=0 LDS row ----
        {
            int o   = tid >> 5;                   // 0..7
            int sub = tid & 31;                   // 32 threads per o
            const u16* row = lds + (o * NDEG) * PB_LS + sub * 4;
            float s = bf2f(row[0]) + bf2f(row[1]) + bf2f(row[2]) + bf2f(row[3]);
#pragma unroll
            for (int m = 16; m >= 1; m >>= 1)     // stays within 32-lane halves
                s += __shfl_xor(s, m, 64);
            if (sub == 0)                         // deterministic partials
                Pr[(size_t)(bb & 7) * ODIM + o0 + o] = s;
        }

#pragma unroll
        for (int t = 0; t < 9; ++t) {             // 72*32 u64 groups / 256 thr
            int g   = t * 256 + tid;
            int j   = g >> 5;                     // 0..71
            int ii4 = (g & 31) << 2;
            int o   = j / NDEG;
            int d   = j - o * NDEG;
            if (d != 0) {
                u64 v = *(const u64*)(lds + j * PB_LS + ii4);
                *(u64*)(Bt + (size_t)(o0 + o) * KA + (d - 1) * 1024 + i0 + ii4) = v;
            }
        }
    } else {
        // ---- A basis (planes d=1..8): thread handles 8 consecutive i ----
        int t  = (bb - NB_B) * 256 + tid;         // 0..524287
        int b  = t >> 7;
        int i8 = (t & 127) << 3;
        const float4* xv = (const float4*)(x + ((size_t)t << 3));
        float4 xa = xv[0], xb = xv[1];
        float th[8] = {fast_tanh(xa.x), fast_tanh(xa.y),
                       fast_tanh(xa.z), fast_tanh(xa.w),
                       fast_tanh(xb.x), fast_tanh(xb.y),
                       fast_tanh(xb.z), fast_tanh(xb.w)};
        float va[8], vb[8];
#pragma unroll
        for (int j = 0; j < 8; ++j) { va[j] = 2.0f; vb[j] = th[j]; }
        u16* dst = A + (size_t)b * KA + i8;
        uint4 w;
        w.x = pack2bf(th[0], th[1]); w.y = pack2bf(th[2], th[3]);
        w.z = pack2bf(th[4], th[5]); w.w = pack2bf(th[6], th[7]);
        *(uint4*)dst = w;                          // d=1 plane
#pragma unroll
        for (int d = 2; d < NDEG; ++d) {
            float nx[8];
#pragma unroll
            for (int j = 0; j < 8; ++j) {
                nx[j] = th[j] * vb[j] + va[j];
                va[j] = vb[j]; vb[j] = nx[j];
            }
            w.x = pack2bf(nx[0], nx[1]); w.y = pack2bf(nx[2], nx[3]);
            w.z = pack2bf(nx[4], nx[5]); w.w = pack2bf(nx[6], nx[7]);
            *(uint4*)(dst + (size_t)(d - 1) * 1024) = w;
        }
    }
}

// ---------------------------------------------------------------------------
// GEMM: P[z][m][n] = A[m][k] * Bt[n][k] over K half (d=1..4 | d=5..8),
// 128x128 tile, BK=64, 4 waves of 64x64 — R0-verified structure (930 TF,
// 74 us, MfmaUtil 37%, 0 bank conflicts, FETCH at compulsory floor).
// DO NOT touch the schedule (8-phase ports falsified in R1/R2).
// z=0 writes straight to out; z=1 writes the single P plane.
// ---------------------------------------------------------------------------
__global__ __launch_bounds__(256, 2)
void gemm_kernel(const u16* __restrict__ A, const u16* __restrict__ B,
                 float* __restrict__ P, float* __restrict__ out) {
    __shared__ __align__(16) u16 ldsA[128 * 64];  // 16 KB
    __shared__ __align__(16) u16 ldsB[128 * 64];  // 16 KB

    const int tid  = threadIdx.x;
    const int lane = tid & 63;
    const int wave = tid >> 6;
    const int quad = lane >> 4;
    const int l15  = lane & 15;
    const int wm   = wave & 1;
    const int wn   = wave >> 1;

    const int bid = blockIdx.x;                   // 0..511
    const int xcd = bid & 7;
    const int loc = bid >> 3;                     // 0..63
    const int z   = xcd >> 2;
    const int bm  = ((xcd & 3) << 3) | (loc >> 3);
    const int bn  = loc & 7;
    const int kStart = z * KAH;

    const u16* ga[4]; const u16* gb[4];
    u16* la[4]; u16* lb[4];
#pragma unroll
    for (int t = 0; t < 4; ++t) {
        int s  = t * 256 + tid;                   // 16B slot in tile, 0..1023
        int r  = s >> 3;                          // tile row 0..127
        int sc = (s & 7) ^ (r & 7);               // source k-chunk (XOR swizzle)
        ga[t] = A + (size_t)(bm * 128 + r) * KA + kStart + sc * 8;
        gb[t] = B + (size_t)(bn * 128 + r) * KA + kStart + sc * 8;
        la[t] = ldsA + s * 8;
        lb[t] = ldsB + s * 8;
    }

    f32x4 acc[4][4];
#pragma unroll
    for (int mt = 0; mt < 4; ++mt)
#pragma unroll
        for (int nt = 0; nt < 4; ++nt)
            acc[mt][nt] = (f32x4){0.f, 0.f, 0.f, 0.f};

    const int nIter = KAH / 64;                   // 64
    for (int it = 0; it < nIter; ++it) {
#pragma unroll
        for (int t = 0; t < 4; ++t) gl_lds16(ga[t], la[t]);
#pragma unroll
        for (int t = 0; t < 4; ++t) gl_lds16(gb[t], lb[t]);
        __syncthreads();

#pragma unroll
        for (int kk = 0; kk < 2; ++kk) {
            short8_t af[4], bfg[4];
#pragma unroll
            for (int mt = 0; mt < 4; ++mt) {
                int row = wm * 64 + mt * 16 + l15;
                int pc  = (kk * 4 + quad) ^ (row & 7);
                af[mt] = *(const short8_t*)(ldsA + (row * 8 + pc) * 8);
            }
#pragma unroll
            for (int nt = 0; nt < 4; ++nt) {
                int row = wn * 64 + nt * 16 + l15;
                int pc  = (kk * 4 + quad) ^ (row & 7);
                bfg[nt] = *(const short8_t*)(ldsB + (row * 8 + pc) * 8);
            }
#pragma unroll
            for (int mt = 0; mt < 4; ++mt)
#pragma unroll
                for (int nt = 0; nt < 4; ++nt)
                    acc[mt][nt] = __builtin_amdgcn_mfma_f32_16x16x32_bf16(
                        af[mt], bfg[nt], acc[mt][nt], 0, 0, 0);
        }
        __syncthreads();

#pragma unroll
        for (int t = 0; t < 4; ++t) { ga[t] += 64; gb[t] += 64; }
    }

    // epilogue: C/D layout col = lane&15, row = quad*4 + reg  [m89-verified]
    float* C = (z == 0) ? out : P;
#pragma unroll
    for (int mt = 0; mt < 4; ++mt) {
#pragma unroll
        for (int nt = 0; nt < 4; ++nt) {
            int row0 = bm * 128 + wm * 64 + mt * 16 + quad * 4;
            int col  = bn * 128 + wn * 64 + nt * 16 + l15;
#pragma unroll
            for (int r = 0; r < 4; ++r)
                C[(size_t)(row0 + r) * ODIM + col] = acc[mt][nt][r];
        }
    }
}

// out = out(z0) + P(z1) + 2 * sum_blk Pr[blk][o]   (split-K + rank-1 d=0 term)
__global__ void reduce_kernel(const float* __restrict__ P,
                              const float* __restrict__ Pr,
                              float* __restrict__ out) {
    int t  = blockIdx.x * 256 + threadIdx.x;      // over BATCH*ODIM/4
    int o4 = t & 255;                             // f32x4 column index
    f32x4 a = ((const f32x4*)out)[t];             // z=0 partial (L3-hot)
    a += ((const f32x4*)P)[t];                    // z=1 partial (L3-hot)
    f32x4 r = (f32x4){0.f, 0.f, 0.f, 0.f};
#pragma unroll
    for (int blk = 0; blk < 8; ++blk)
        r += ((const f32x4*)Pr)[blk * 256 + o4];  // hot in L2 (32 KB table)
    ((f32x4*)out)[t] = a + r + r;                 // + 2*r  (V0 = 2)
}

extern "C" void kernel_launch(void* const* d_in, const int* in_sizes, int n_in,
                              void* d_out, int out_size, void* d_ws, size_t ws_size,
                              hipStream_t stream) {
    const float* x      = (const float*)d_in[0];   // [4096,1024] f32
    const float* coeffs = (const float*)d_in[1];   // [1024,1024,9] f32
    float* out = (float*)d_out;                    // [4096,1024] f32
    (void)ws_size;

    u16*   A  = (u16*)d_ws;                        // 67.1 MB
    u16*   Bt = A + (size_t)BATCH * KA;            // 16.8 MB
    float* Pr = (float*)(Bt + (size_t)ODIM * KA);  // 32 KB rank-1 partials
    float* P  = Pr + 8 * ODIM;                     // 16.8 MB (1 split-K plane)
    // total ws: 100.8 MB

    prep_kernel<<<NB_B + NB_A, 256, 0, stream>>>(x, coeffs, A, Bt, Pr);
    gemm_kernel<<<512, 256, 0, stream>>>(A, Bt, P, out);
    reduce_kernel<<<BATCH * ODIM / 1024, 256, 0, stream>>>(P, Pr, out);
}